// Round 17
// baseline (97.166 us; speedup 1.0000x reference)
//
#include <hip/hip_runtime.h>
#include <hip/hip_bf16.h>

// DIAGNOSTIC BUILD (v17): v14 (best, 16.65us) with the whole body repeated
// 12x via an opaque loop (asm "+v" offsets defeat cross-rep CSE/hoisting).
// Each rep does identical work and stores identical values -> correct and
// deterministic, but ~12x kernel time -> forces our kernel into rocprof's
// top-5 (harness fill kernels at ~40us masked it in ALL prior rounds).
// Goals: (1) measure fixed per-invocation overhead = harness_dur - dispatch
// dur; (2) finally read hbm_gbps/VALUBusy/MfmaUtil/Occupancy for the hot
// kernel. Perf this round is sacrificed by design.

typedef __attribute__((ext_vector_type(8))) short bf16x8;
typedef __attribute__((ext_vector_type(4))) float f32x4;

__device__ __forceinline__ unsigned short f2bf(float v) {
    unsigned u = __float_as_uint(v);
    u += 0x7FFF + ((u >> 16) & 1);
    return (unsigned short)(u >> 16);
}

__global__ __launch_bounds__(256, 2) void fused_mfma_kernel(const float* __restrict__ x,
                                                            const float* __restrict__ w,
                                                            float* __restrict__ out) {
    __shared__ __align__(16) unsigned short es[64 * 328];    // 42.0 KB
    __shared__ __align__(16) unsigned short ws_[10 * 640];   // 12.8 KB
    __shared__ float lcs[160];

    const int tid = threadIdx.x;
    const int d   = blockIdx.x & 255;
    const int nb  = (blockIdx.x >> 8) << 6;      // 0 or 64

    int xoff = 0, woff = 0;                      // stay 0; opaque to compiler
#pragma unroll 1
    for (int rep = 0; rep < 12; ++rep) {
        asm volatile("" : "+v"(xoff), "+v"(woff));

        // ---- phase 1: stage x (packed b64 writes) + w + pad zeros -----------
        {
            const int n_l = tid >> 2;
            const int seg = tid & 3;
            const float* xg = x + xoff + ((nb + n_l) * 256 + d) * 160 + seg * 40;
            float4 xv[10];
#pragma unroll
            for (int k = 0; k < 10; ++k) xv[k] = *reinterpret_cast<const float4*>(xg + 4 * k);

            const float* wgp = w + woff + d * 2560 + tid * 10;
            float wv[10];
#pragma unroll
            for (int k = 0; k < 5; ++k) {
                float2 v = *reinterpret_cast<const float2*>(wgp + 2 * k);
                wv[2 * k] = v.x; wv[2 * k + 1] = v.y;
            }

            const float* xf = reinterpret_cast<const float*>(xv);
#pragma unroll
            for (int r = 0; r < 10; ++r) {
                unsigned short s0 = f2bf(__expf(xf[r]));
                unsigned short s1 = f2bf(__expf(xf[10 + r]));
                unsigned short s2 = f2bf(__expf(xf[20 + r]));
                unsigned short s3 = f2bf(__expf(xf[30 + r]));
                const unsigned lo = (unsigned)s0 | ((unsigned)s1 << 16);
                const unsigned hi = (unsigned)s2 | ((unsigned)s3 << 16);
                unsigned* dst = reinterpret_cast<unsigned*>(&es[n_l * 328 + r * 32 + 4 * seg]);
                *reinterpret_cast<uint2*>(dst) = make_uint2(lo, hi);
                unsigned* pad = reinterpret_cast<unsigned*>(&es[n_l * 328 + r * 32 + 16 + 4 * seg]);
                *reinterpret_cast<uint2*>(pad) = make_uint2(0u, 0u);
            }
#pragma unroll
            for (int k = 0; k < 10; ++k) {
                const int off = tid * 10 + k;
                const int ic  = off / 160;
                const int rem = off - ic * 160;
                const int oc  = rem / 10;
                const int r   = rem - oc * 10;
                ws_[r * 640 + oc * 40 + ic] = f2bf(__expf(wv[k]));
            }
            if (tid < 160) {
                const int r = tid >> 4, oc = tid & 15;
                uint4* p = reinterpret_cast<uint4*>(&ws_[r * 640 + oc * 40 + 16]);
                const uint4 z = make_uint4(0u, 0u, 0u, 0u);
                p[0] = z; p[1] = z;
            }
        }
        __syncthreads();

        // ---- phase 2: lcs + MFMAs -------------------------------------------
        if (tid < 160) {
            const int oc = tid / 10, r = tid - (tid / 10) * 10;
            const unsigned short* p = &ws_[r * 640 + oc * 40];
            float s = 0.f;
#pragma unroll
            for (int ic = 0; ic < 16; ++ic)
                s += __uint_as_float(((unsigned)p[ic]) << 16);
            lcs[oc * 10 + r] = __logf(s);
        }

        const int mt = tid >> 6;
        const int l  = tid & 63;
        const int lm = l & 15;
        const int kg = l >> 4;

        const int abase = (mt * 16 + lm) * 328 + kg * 8;
        const int bbase = lm * 40 + kg * 8;

        f32x4 acc[10];
        const f32x4 zero = {0.f, 0.f, 0.f, 0.f};
#pragma unroll
        for (int r = 0; r < 10; ++r) {
            bf16x8 a = *reinterpret_cast<const bf16x8*>(&es[abase + r * 32]);
            bf16x8 b = *reinterpret_cast<const bf16x8*>(&ws_[r * 640 + bbase]);
            acc[r] = __builtin_amdgcn_mfma_f32_16x16x32_bf16(a, b, zero, 0, 0, 0);
        }
        __syncthreads();   // lcs visible

        // ---- phase 3: epilogue, direct coalesced stores ---------------------
        float lc[10];
#pragma unroll
        for (int r = 0; r < 10; ++r) lc[r] = lcs[lm * 10 + r];

#pragma unroll
        for (int j = 0; j < 4; ++j) {
            const int n = mt * 16 + kg * 4 + j;
            float* og = out + ((nb + n) * 256 + d) * 160 + lm * 10;
#pragma unroll
            for (int h = 0; h < 5; ++h) {
                float2 o;
                o.x = __logf(acc[2 * h][j])     - lc[2 * h];
                o.y = __logf(acc[2 * h + 1][j]) - lc[2 * h + 1];
                *reinterpret_cast<float2*>(og + 2 * h) = o;
            }
        }
        __syncthreads();   // es/ws_ reads done before next rep's writes
    }
}

extern "C" void kernel_launch(void* const* d_in, const int* in_sizes, int n_in,
                              void* d_out, int out_size, void* d_ws, size_t ws_size,
                              hipStream_t stream) {
    const float* x = (const float*)d_in[0];
    const float* w = (const float*)d_in[1];
    float* out = (float*)d_out;

    fused_mfma_kernel<<<512, 256, 0, stream>>>(x, w, out);
}

// Round 18
// 16.716 us; speedup vs baseline: 5.8129x; 5.8129x over previous
//
#include <hip/hip_runtime.h>
#include <hip/hip_bf16.h>

// Problem dims (fixed): n=128, d=256, ic=16, oc=16, r=10
// x:   [n, d, ic, r]  f32; w: [d, ic, oc, r] f32; out: [n, d, oc, r] f32
// out[n,d,oc,r] = log( sum_ic exp(x)*exp(w) ) - log( sum_ic exp(w) )
//
// v18 (from v17 diagnostics: Occupancy 17%, VALUBusy 35%, hbm 42%, LDS
// conflicts 5.1M — latency-bound at 2 blocks/CU):
//  - es stores only slots 0..15 (10.5 KB); A-side K-pad = zero REGS for
//    kg>=2 lanes (v16-verified). B-side zeros kept in LDS (0 x garbage-NaN
//    would poison acc).
//  - block = (d, 32n), 256 thr, grid 1024 -> 24 KB LDS, 4 blocks/CU,
//    16 waves/CU (2x occupancy), 4 desynced blocks per CU.
//  - all 4 waves MFMA: wave = (m-tile, r-half), 5 MFMAs each.
//  - lcs threads remapped (r,oc) + b128 row reads: 10-way conflict -> ~2-way.
//  - same-d blocks share XCD (bid step 256 = 0 mod 8): w reads L2-local.

typedef __attribute__((ext_vector_type(8))) short bf16x8;
typedef __attribute__((ext_vector_type(4))) float f32x4;

__device__ __forceinline__ unsigned short f2bf(float v) {
    unsigned u = __float_as_uint(v);
    u += 0x7FFF + ((u >> 16) & 1);
    return (unsigned short)(u >> 16);
}

__global__ __launch_bounds__(256, 4) void fused_mfma_kernel(const float* __restrict__ x,
                                                            const float* __restrict__ w,
                                                            float* __restrict__ out) {
    __shared__ __align__(16) unsigned short es[32 * 168];    // 10.5 KB [n_l][r*16+ic]
    __shared__ __align__(16) unsigned short ws_[10 * 640];   // 12.8 KB [r][oc*40+slot]
    __shared__ float lcs[160];                               // [oc*10+r]

    const int tid = threadIdx.x;
    const int d   = blockIdx.x & 255;
    const int n_b = (blockIdx.x >> 8) << 5;      // 0,32,64,96

    // ---- phase 1: stage exp(x) (16 slots only) + exp(w) + B-pad zeros ------
    {
        const int n_l  = tid >> 3;               // 0..31
        const int part = tid & 7;                // ic pair (2part, 2part+1)
        const float* xg = x + ((n_b + n_l) * 256 + d) * 160 + part * 20;
        float4 xv[5];
#pragma unroll
        for (int k = 0; k < 5; ++k) xv[k] = *reinterpret_cast<const float4*>(xg + 4 * k);
        const float* xf = reinterpret_cast<const float*>(xv);
        unsigned short* erow = &es[n_l * 168];
#pragma unroll
        for (int r = 0; r < 10; ++r) {
            const unsigned v = (unsigned)f2bf(__expf(xf[r])) |
                               ((unsigned)f2bf(__expf(xf[10 + r])) << 16);
            *reinterpret_cast<unsigned*>(&erow[r * 16 + part * 2]) = v;
        }

        // w: thread = (ic = tid>>4, oc = tid&15), all 10 r (40B contiguous)
        const float* wgp = w + d * 2560 + tid * 10;
        float wv[10];
#pragma unroll
        for (int k = 0; k < 5; ++k) {
            float2 v2 = *reinterpret_cast<const float2*>(wgp + 2 * k);
            wv[2 * k] = v2.x; wv[2 * k + 1] = v2.y;
        }
        const int ic = tid >> 4, oc = tid & 15;
#pragma unroll
        for (int r = 0; r < 10; ++r)
            ws_[r * 640 + oc * 40 + ic] = f2bf(__expf(wv[r]));

        if (tid < 160) {                         // zero B slots 16..31
            const int r2 = tid >> 4, oc2 = tid & 15;
            uint4* p = reinterpret_cast<uint4*>(&ws_[r2 * 640 + oc2 * 40 + 16]);
            const uint4 z = make_uint4(0u, 0u, 0u, 0u);
            p[0] = z; p[1] = z;
        }
    }
    __syncthreads();

    // ---- phase 2: lcs (bank-friendly (r,oc) map) + MFMAs (all 4 waves) -----
    if (tid < 160) {
        const int r = tid >> 4, oc = tid & 15;
        const unsigned short* p = &ws_[r * 640 + oc * 40];
        const uint4 q0 = *reinterpret_cast<const uint4*>(p);
        const uint4 q1 = *reinterpret_cast<const uint4*>(p + 8);
        const unsigned qs[8] = {q0.x, q0.y, q0.z, q0.w, q1.x, q1.y, q1.z, q1.w};
        float s = 0.f;
#pragma unroll
        for (int i = 0; i < 8; ++i) {
            s += __uint_as_float(qs[i] << 16);
            s += __uint_as_float(qs[i] & 0xFFFF0000u);
        }
        lcs[oc * 10 + r] = __logf(s);
    }

    const int wid = tid >> 6;
    const int mt  = wid & 1;             // m-tile (16 n)
    const int rh  = wid >> 1;            // r-half
    const int l   = tid & 63;
    const int lm  = l & 15;              // oc / A-row
    const int kg  = l >> 4;              // k-group

    const bf16x8 zero8 = {0, 0, 0, 0, 0, 0, 0, 0};
    const f32x4  zeroc = {0.f, 0.f, 0.f, 0.f};
    f32x4 acc[5];
#pragma unroll
    for (int h = 0; h < 5; ++h) {
        const int r = rh * 5 + h;
        bf16x8 a = (kg < 2)
            ? *reinterpret_cast<const bf16x8*>(&es[(mt * 16 + lm) * 168 + r * 16 + kg * 8])
            : zero8;
        bf16x8 b = *reinterpret_cast<const bf16x8*>(&ws_[r * 640 + lm * 40 + kg * 8]);
        acc[h] = __builtin_amdgcn_mfma_f32_16x16x32_bf16(a, b, zeroc, 0, 0, 0);
    }
    __syncthreads();   // lcs visible

    // ---- phase 3: epilogue; C row=kg*4+j, col=lm (m89-verified) -------------
    float lc[5];
#pragma unroll
    for (int h = 0; h < 5; ++h) lc[h] = lcs[lm * 10 + rh * 5 + h];

#pragma unroll
    for (int j = 0; j < 4; ++j) {
        const int n = n_b + mt * 16 + kg * 4 + j;
        float* og = out + (n * 256 + d) * 160 + lm * 10 + rh * 5;
        float o[5];
#pragma unroll
        for (int h = 0; h < 5; ++h) o[h] = __logf(acc[h][j]) - lc[h];
        if (rh == 0) {   // byte base 40*lm: 8-aligned
            *reinterpret_cast<float2*>(og)     = make_float2(o[0], o[1]);
            *reinterpret_cast<float2*>(og + 2) = make_float2(o[2], o[3]);
            og[4] = o[4];
        } else {         // byte base 40*lm+20: f1, then 8-aligned f2 pairs
            og[0] = o[0];
            *reinterpret_cast<float2*>(og + 1) = make_float2(o[1], o[2]);
            *reinterpret_cast<float2*>(og + 3) = make_float2(o[3], o[4]);
        }
    }
}

extern "C" void kernel_launch(void* const* d_in, const int* in_sizes, int n_in,
                              void* d_out, int out_size, void* d_ws, size_t ws_size,
                              hipStream_t stream) {
    const float* x = (const float*)d_in[0];
    const float* w = (const float*)d_in[1];
    float* out = (float*)d_out;

    // 1024 blocks: d = bid&255, n-chunk = bid>>8 (4 chunks of 32 n)
    fused_mfma_kernel<<<1024, 256, 0, stream>>>(x, w, out);
}